// Round 4
// baseline (184.712 us; speedup 1.0000x reference)
//
#include <hip/hip_runtime.h>
#include <stdint.h>

typedef __bf16 bf16;
typedef __bf16 bf16x8 __attribute__((ext_vector_type(8)));
typedef __bf16 bf16x4 __attribute__((ext_vector_type(4)));
typedef _Float16 f16;
typedef f16 f16x8 __attribute__((ext_vector_type(8)));
typedef f16 f16x4 __attribute__((ext_vector_type(4)));
typedef f16 f16x2 __attribute__((ext_vector_type(2)));
typedef float f32x4 __attribute__((ext_vector_type(4)));
typedef float f32x16 __attribute__((ext_vector_type(16)));
typedef uint32_t u32x4 __attribute__((ext_vector_type(4)));

#define LQ    16384   // B*L total rows
#define CDIM  1024
#define DDIM  128
#define NSPLIT 4
#define QS 0.12751741f   // (1/sqrt(128)) * log2(e): folded into Q -> softmax uses exp2

static __device__ __forceinline__ uint32_t pkrtz(float a, float b) {
  return __builtin_bit_cast(uint32_t, __builtin_amdgcn_cvt_pkrtz(a, b));
}

// ---------------- K0: Wt[3][128][1024] (bf16, Q rows prescaled) + bias_all[384]
__global__ void prep_kernel(const float* __restrict__ Wq, const float* __restrict__ Wk,
                            const float* __restrict__ Wv, const float* __restrict__ bq,
                            const float* __restrict__ bk, const float* __restrict__ bv,
                            bf16* __restrict__ Wt, float* __restrict__ bias_all) {
  int idx = blockIdx.x * 256 + threadIdx.x;      // 0 .. 3*131072
  int p = idx >> 17;
  int rem = idx & 131071;
  int k = rem >> 7, n = rem & 127;
  const float* W = (p == 0) ? Wq : (p == 1) ? Wk : Wv;
  float s = (p == 0) ? QS : 1.0f;
  Wt[(size_t)(p * 128 + n) * CDIM + k] = (bf16)(W[rem] * s);
  if (idx < 384) {
    int pp = idx >> 7, nn = idx & 127;
    const float* b = (pp == 0) ? bq : (pp == 1) ? bk : bv;
    bias_all[idx] = b[nn] * ((pp == 0) ? QS : 1.0f);
  }
}

// ---------------- K1: QKV GEMM, BM=128 BN=64 BK=64, grid 768 = 3 blocks/CU ---
// 256 thr / 4 waves, wave tile 64x32 via 32x32x16 bf16 MFMA.
// LDS 48 KB (no pad) with T2 XOR swizzle at 8-elem granule on A and B
// (write g^=row&7, read same involution) -> capacity-balanced ds_read_b128.
// XCD chunk map: the 6 blocks (3 proj x 2 n) sharing one x m-panel co-reside
// on one XCD so x re-reads are L2 hits.
__global__ __launch_bounds__(256, 3) void qkv_gemm(
    const float* __restrict__ x, const bf16* __restrict__ Wt,
    const float* __restrict__ bias_all,
    bf16* __restrict__ Qw, bf16* __restrict__ Kw, f16* __restrict__ Vtw) {
  __shared__ bf16 As[2][128 * 64];   // [m][k] swizzled, 16 KB each
  __shared__ bf16 Bs[2][64 * 64];    // [n][k] swizzled, 8 KB each
  const int t = threadIdx.x;
  const int w = t >> 6;
  const int lane = t & 63;
  const int l31 = lane & 31;
  const int hi = lane >> 5;
  // 768 blocks -> bijective XCD chunk map (96 logical / XCD)
  const int lin = blockIdx.x;
  const int logical = (lin & 7) * 96 + (lin >> 3);
  const int mi = logical / 6;          // 0..127
  const int rr = logical % 6;
  const int y = rr >> 1;               // projection 0..2
  const int nb = rr & 1;               // n-block 0..1
  const int m0 = mi * 128;
  const int n0 = nb * 64;
  const bf16* W = Wt + (size_t)y * (DDIM * CDIM) + (size_t)n0 * CDIM;
  const int m_off = (w & 1) * 64;
  const int n_off = (w >> 1) * 32;

  const f32x16 z16 = {0.f,0.f,0.f,0.f,0.f,0.f,0.f,0.f,0.f,0.f,0.f,0.f,0.f,0.f,0.f,0.f};
  f32x16 acc[2];
  acc[0] = z16; acc[1] = z16;

  // staging geometry: row = c*32 + (t>>3), col granule g = t&7 (8 bf16 = 16 B)
  const int srow = t >> 3;             // 0..31
  const int g = t & 7;
  const int sg = (g ^ (srow & 7)) * 8; // swizzled granule offset (same all chunks)
  const int scol = g * 8;              // global column base

  float4 xa[4][2];
  bf16x8 wa[2];
#pragma unroll
  for (int c = 0; c < 4; c++) {
    const float* p = &x[(size_t)(m0 + c * 32 + srow) * CDIM + scol];
    xa[c][0] = *(const float4*)p;
    xa[c][1] = *(const float4*)(p + 4);
  }
#pragma unroll
  for (int c = 0; c < 2; c++)
    wa[c] = *(const bf16x8*)&W[(size_t)(c * 32 + srow) * CDIM + scol];

  for (int kc = 0; kc < 16; kc++) {
    bf16* Ab = As[kc & 1];
    bf16* Bb = Bs[kc & 1];
#pragma unroll
    for (int c = 0; c < 4; c++) {
      bf16x8 v;
      v[0] = (bf16)xa[c][0].x; v[1] = (bf16)xa[c][0].y;
      v[2] = (bf16)xa[c][0].z; v[3] = (bf16)xa[c][0].w;
      v[4] = (bf16)xa[c][1].x; v[5] = (bf16)xa[c][1].y;
      v[6] = (bf16)xa[c][1].z; v[7] = (bf16)xa[c][1].w;
      *(bf16x8*)&Ab[(c * 32 + srow) * 64 + sg] = v;
    }
#pragma unroll
    for (int c = 0; c < 2; c++)
      *(bf16x8*)&Bb[(c * 32 + srow) * 64 + sg] = wa[c];

    const int kn = (kc < 15 ? kc + 1 : 15) * 64;   // clamped prefetch
#pragma unroll
    for (int c = 0; c < 4; c++) {
      const float* p = &x[(size_t)(m0 + c * 32 + srow) * CDIM + kn + scol];
      xa[c][0] = *(const float4*)p;
      xa[c][1] = *(const float4*)(p + 4);
    }
#pragma unroll
    for (int c = 0; c < 2; c++)
      wa[c] = *(const bf16x8*)&W[(size_t)(c * 32 + srow) * CDIM + kn + scol];

    __syncthreads();

#pragma unroll
    for (int ks = 0; ks < 4; ks++) {
      const int rg = ((ks * 2 + hi) ^ (l31 & 7)) * 8;   // swizzled read granule
      bf16x8 bfr = *(const bf16x8*)&Bb[(n_off + l31) * 64 + rg];
      bf16x8 af0 = *(const bf16x8*)&Ab[(m_off + l31) * 64 + rg];
      bf16x8 af1 = *(const bf16x8*)&Ab[(m_off + 32 + l31) * 64 + rg];
      acc[0] = __builtin_amdgcn_mfma_f32_32x32x16_bf16(af0, bfr, acc[0], 0, 0, 0);
      acc[1] = __builtin_amdgcn_mfma_f32_32x32x16_bf16(af1, bfr, acc[1], 0, 0, 0);
    }
  }

  const float bias = bias_all[y * 128 + n0 + n_off + l31];
  const int n = n0 + n_off + l31;

  if (y < 2) {
    bf16* outp = (y == 0) ? Qw : Kw;
#pragma unroll
    for (int mt = 0; mt < 2; mt++)
#pragma unroll
      for (int r = 0; r < 16; r++) {
        int m = m0 + m_off + mt * 32 + (r & 3) + 8 * (r >> 2) + 4 * hi;
        outp[(size_t)m * DDIM + n] = (bf16)(acc[mt][r] + bias);
      }
  } else {
#pragma unroll
    for (int mt = 0; mt < 2; mt++)
#pragma unroll
      for (int gq = 0; gq < 4; gq++) {
        int mbase = m0 + m_off + mt * 32 + 8 * gq + 4 * hi;
        f16x4 pv;
#pragma unroll
        for (int r = 0; r < 4; r++) pv[r] = (f16)(acc[mt][gq * 4 + r] + bias);
        *(f16x4*)&Vtw[(size_t)n * LQ + mbase] = pv;
      }
  }
}

// ---------------- K2: flash attention, 32x32 MFMA path ----------------------
// grid (128 q-blocks of 128 rows, 4 KV quarters), 256 thr (4 waves x 32 q rows).
// S^T = K·Q^T via 32x32x16 bf16 (C: row=kv=(r&3)+8(r>>2)+4hi, col=q=l31).
// P redistribution to PV A-frag: cvt_pkrtz pairs + v_permlane32_swap_b32.
// PV via full-rate 32x32x16 f16; V read as contiguous f16x8 from Vl[d][kv].
__global__ __launch_bounds__(256, 2) void flash_kernel(
    const bf16* __restrict__ Qw, const bf16* __restrict__ Kw, const f16* __restrict__ Vtw,
    bf16* __restrict__ Opb, float* __restrict__ lp) {
  __shared__ bf16 Kl[2][64 * 136];    // [kv][d] pad 128->136
  __shared__ f16  Vl[2][128 * 72];    // [d][kv] pad 64->72

  const int t = threadIdx.x;
  const int w = t >> 6;
  const int lane = t & 63;
  const int l31 = lane & 31;
  const int hi = lane >> 5;
  // 512 blocks, bijective XCD chunk map: q-blocks sharing a KV panel co-reside per XCD
  const int lin = blockIdx.y * 128 + blockIdx.x;
  const int logical = ((lin & 7) << 6) + (lin >> 3);
  const int qb = logical & 127;       // 0..127
  const int sp = logical >> 7;        // 0..3
  const int batch = qb >> 5;
  const int q0w = qb * 128 + w * 32;
  const int kv_base = batch * 4096 + sp * 1024;

  // Q fragments (B-operand of S^T, 32x32x16): col=q=l31, k = ks*16 + hi*8 + j
  bf16x8 qf[8];
#pragma unroll
  for (int ks = 0; ks < 8; ks++)
    qf[ks] = *(const bf16x8*)&Qw[(size_t)(q0w + l31) * DDIM + ks * 16 + hi * 8];

  const f32x16 z16 = {0.f,0.f,0.f,0.f,0.f,0.f,0.f,0.f,0.f,0.f,0.f,0.f,0.f,0.f,0.f,0.f};
  f32x16 o[4];                        // O: row q=crow(r,hi), col d=dt*32+l31
  o[0] = z16; o[1] = z16; o[2] = z16; o[3] = z16;
  f32x16 liacc = z16;                 // row sums, row q=crow(r,hi)

  f16x8 ones;
#pragma unroll
  for (int i = 0; i < 8; i++) ones[i] = (f16)1.f;

  const int kr = t >> 4;              // 0..15 (+c*16)
  const int kcol = (t & 15) << 3;
  const int vr = t >> 3;              // 0..31 (+c*32)
  const int vcol = (t & 7) << 3;

  bf16x8 ka[4];
  f16x8 va[4];
#pragma unroll
  for (int c = 0; c < 4; c++)
    ka[c] = *(const bf16x8*)&Kw[(size_t)(kv_base + c * 16 + kr) * DDIM + kcol];
#pragma unroll
  for (int c = 0; c < 4; c++)
    va[c] = *(const f16x8*)&Vtw[(size_t)(c * 32 + vr) * LQ + kv_base + vcol];

  for (int tile = 0; tile < 16; tile++) {
    bf16* Kb = Kl[tile & 1];
    f16*  Vb = Vl[tile & 1];
#pragma unroll
    for (int c = 0; c < 4; c++)
      *(bf16x8*)&Kb[(c * 16 + kr) * 136 + kcol] = ka[c];
#pragma unroll
    for (int c = 0; c < 4; c++)
      *(f16x8*)&Vb[(c * 32 + vr) * 72 + vcol] = va[c];

    const int kvn = kv_base + (tile < 15 ? tile + 1 : 15) * 64;  // clamped prefetch
#pragma unroll
    for (int c = 0; c < 4; c++)
      ka[c] = *(const bf16x8*)&Kw[(size_t)(kvn + c * 16 + kr) * DDIM + kcol];
#pragma unroll
    for (int c = 0; c < 4; c++)
      va[c] = *(const f16x8*)&Vtw[(size_t)(c * 32 + vr) * LQ + kvn + vcol];

    __syncthreads();   // staging of this tile visible; prev-tile reads done (1 barrier/tile)

    // S^T = K·Q^T : sv_mk element (kv = mk*32 + (r&3)+8*(r>>2)+4*hi, q = l31)
    f32x16 sv0 = z16, sv1 = z16;
    __builtin_amdgcn_s_setprio(1);
#pragma unroll
    for (int ks = 0; ks < 8; ks++) {
      bf16x8 kf0 = *(const bf16x8*)&Kb[l31 * 136 + ks * 16 + hi * 8];
      bf16x8 kf1 = *(const bf16x8*)&Kb[(32 + l31) * 136 + ks * 16 + hi * 8];
      sv0 = __builtin_amdgcn_mfma_f32_32x32x16_bf16(kf0, qf[ks], sv0, 0, 0, 0);
      sv1 = __builtin_amdgcn_mfma_f32_32x32x16_bf16(kf1, qf[ks], sv1, 0, 0, 0);
    }
    __builtin_amdgcn_s_setprio(0);

    // P = exp2(S) — no max subtraction (scores O(1) by construction)
#pragma unroll
    for (int r = 0; r < 16; r++) {
      sv0[r] = __builtin_amdgcn_exp2f(sv0[r]);
      sv1[r] = __builtin_amdgcn_exp2f(sv1[r]);
    }

    // P^T(kv,q) -> PV A-frag (row=q=l31, k=kv): pack pairs, permlane32_swap.
#pragma unroll
    for (int mk = 0; mk < 2; mk++) {
      const f32x16 s = mk ? sv1 : sv0;
#pragma unroll
      for (int h = 0; h < 2; h++) {     // K=16 half within the 32-kv block
        const int b = h * 8;
        uint32_t a0 = pkrtz(s[b + 0], s[b + 1]);   // kv base+4hi+{0,1}
        uint32_t a1 = pkrtz(s[b + 2], s[b + 3]);   // kv base+4hi+{2,3}
        uint32_t a2 = pkrtz(s[b + 4], s[b + 5]);   // kv base+8+4hi+{0,1}
        uint32_t a3 = pkrtz(s[b + 6], s[b + 7]);   // kv base+8+4hi+{2,3}
        asm("v_permlane32_swap_b32 %0, %1" : "+v"(a0), "+v"(a2));  // a0->w0, a2->w2
        asm("v_permlane32_swap_b32 %0, %1" : "+v"(a1), "+v"(a3));  // a1->w1, a3->w3
        u32x4 aw; aw.x = a0; aw.y = a1; aw.z = a2; aw.w = a3;
        f16x8 pa = __builtin_bit_cast(f16x8, aw);  // A[q=l31][k=8hi+j]
        __builtin_amdgcn_s_setprio(1);
#pragma unroll
        for (int dt = 0; dt < 4; dt++) {
          f16x8 vf = *(const f16x8*)&Vb[(dt * 32 + l31) * 72 + mk * 32 + h * 16 + hi * 8];
          o[dt] = __builtin_amdgcn_mfma_f32_32x32x16_f16(pa, vf, o[dt], 0, 0, 0);
        }
        liacc = __builtin_amdgcn_mfma_f32_32x32x16_f16(pa, ones, liacc, 0, 0, 0);
        __builtin_amdgcn_s_setprio(0);
      }
    }
  }

  // epilogue: unnormalized O (bf16) + row sums l
  const size_t po = (size_t)sp * LQ * DDIM;
#pragma unroll
  for (int dt = 0; dt < 4; dt++)
#pragma unroll
    for (int r = 0; r < 16; r++) {
      int q = q0w + (r & 3) + 8 * (r >> 2) + 4 * hi;
      Opb[po + (size_t)q * DDIM + dt * 32 + l31] = (bf16)o[dt][r];
    }
  if (l31 == 0) {
#pragma unroll
    for (int r = 0; r < 16; r++)
      lp[(size_t)sp * LQ + q0w + (r & 3) + 8 * (r >> 2) + 4 * hi] = liacc[r];
  }
}

// ---------------- K3: combine: out = (sum O_sp) / (sum l_sp) ----------------
__global__ void combine_kernel(const bf16* __restrict__ Opb, const float* __restrict__ lp,
                               float* __restrict__ out) {
  int idx = blockIdx.x * 256 + threadIdx.x;   // LQ * 32
  int q = idx >> 5;
  int d = (idx & 31) * 4;
  float lsum = 0.f;
  float acc[4] = {0.f, 0.f, 0.f, 0.f};
#pragma unroll
  for (int sp = 0; sp < NSPLIT; sp++) {
    lsum += lp[(size_t)sp * LQ + q];
    bf16x4 ov = *(const bf16x4*)&Opb[(size_t)sp * LQ * DDIM + (size_t)q * DDIM + d];
#pragma unroll
    for (int j = 0; j < 4; j++) acc[j] += (float)ov[j];
  }
  float inv = 1.0f / lsum;
  float4 r;
  r.x = acc[0] * inv; r.y = acc[1] * inv; r.z = acc[2] * inv; r.w = acc[3] * inv;
  *(float4*)&out[(size_t)q * DDIM + d] = r;
}

extern "C" void kernel_launch(void* const* d_in, const int* in_sizes, int n_in,
                              void* d_out, int out_size, void* d_ws, size_t ws_size,
                              hipStream_t stream) {
  const float* x  = (const float*)d_in[0];
  const float* Wq = (const float*)d_in[1];
  const float* bq = (const float*)d_in[2];
  const float* Wk = (const float*)d_in[3];
  const float* bk = (const float*)d_in[4];
  const float* Wv = (const float*)d_in[5];
  const float* bv = (const float*)d_in[6];
  char* ws = (char*)d_ws;
  bf16* Qw   = (bf16*)(ws);                              // 4 MB (prescaled by QS)
  bf16* Kw   = (bf16*)(ws + ((size_t)4 << 20));          // 4 MB
  f16*  Vtw  = (f16*)(ws + ((size_t)8 << 20));           // 4 MB (transposed [d][q], f16)
  bf16* Wt   = (bf16*)(ws + ((size_t)12 << 20));         // 768 KB
  float* bias_all = (float*)(ws + ((size_t)12 << 20) + 786432); // 1.5 KB
  bf16* Opb  = (bf16*)(ws + ((size_t)13 << 20));         // 16 MB (4 splits, bf16)
  float* lpp = (float*)(ws + ((size_t)29 << 20));        // 256 KB
  float* out = (float*)d_out;

  prep_kernel<<<1536, 256, 0, stream>>>(Wq, Wk, Wv, bq, bk, bv, Wt, bias_all);
  qkv_gemm<<<768, 256, 0, stream>>>(x, Wt, bias_all, Qw, Kw, Vtw);
  flash_kernel<<<dim3(128, NSPLIT), 256, 0, stream>>>(Qw, Kw, Vtw, Opb, lpp);
  combine_kernel<<<2048, 256, 0, stream>>>(Opb, lpp, out);
}

// Round 5
// 171.191 us; speedup vs baseline: 1.0790x; 1.0790x over previous
//
#include <hip/hip_runtime.h>
#include <stdint.h>

typedef __bf16 bf16;
typedef __bf16 bf16x8 __attribute__((ext_vector_type(8)));
typedef __bf16 bf16x4 __attribute__((ext_vector_type(4)));
typedef _Float16 f16;
typedef f16 f16x8 __attribute__((ext_vector_type(8)));
typedef f16 f16x4 __attribute__((ext_vector_type(4)));
typedef float f32x4 __attribute__((ext_vector_type(4)));
typedef float f32x16 __attribute__((ext_vector_type(16)));
typedef uint32_t u32x4 __attribute__((ext_vector_type(4)));

#define LQ    16384   // B*L total rows
#define CDIM  1024
#define DDIM  128
#define NSPLIT 4
#define QS 0.12751741f   // (1/sqrt(128)) * log2(e): folded into Q -> softmax uses exp2

static __device__ __forceinline__ uint32_t pkrtz(float a, float b) {
  return __builtin_bit_cast(uint32_t, __builtin_amdgcn_cvt_pkrtz(a, b));
}

// no-drain barrier: LDS visibility only; global loads stay in flight (reg-staged,
// so vmcnt is a private register dependency the compiler tracks with counted waits).
static __device__ __forceinline__ void lds_barrier() {
  asm volatile("s_waitcnt lgkmcnt(0)" ::: "memory");
  __builtin_amdgcn_s_barrier();
}

// ---------------- K0: Wt[3][128][1024] (bf16, Q rows prescaled) + bias_all[384]
__global__ void prep_kernel(const float* __restrict__ Wq, const float* __restrict__ Wk,
                            const float* __restrict__ Wv, const float* __restrict__ bq,
                            const float* __restrict__ bk, const float* __restrict__ bv,
                            bf16* __restrict__ Wt, float* __restrict__ bias_all) {
  int idx = blockIdx.x * 256 + threadIdx.x;      // 0 .. 3*131072
  int p = idx >> 17;
  int rem = idx & 131071;
  int k = rem >> 7, n = rem & 127;
  const float* W = (p == 0) ? Wq : (p == 1) ? Wk : Wv;
  float s = (p == 0) ? QS : 1.0f;
  Wt[(size_t)(p * 128 + n) * CDIM + k] = (bf16)(W[rem] * s);
  if (idx < 384) {
    int pp = idx >> 7, nn = idx & 127;
    const float* b = (pp == 0) ? bq : (pp == 1) ? bk : bv;
    bias_all[idx] = b[nn] * ((pp == 0) ? QS : 1.0f);
  }
}

// ---------------- K1: QKV GEMM, BM=64, BN=384 (all 3 projections per block) --
// grid 256 = 1 block/CU, 512 thr (8 waves, 2m x 4n), wave tile 32x32 x 3 proj.
// x read ONCE total (67 MB HBM stream, disjoint panels -> no L2 thrash);
// W (768 KB) L2-resident per XCD. LDS 112 KB dbuf, XOR-swizzled granules.
// No-drain lds_barrier: loads issued pre-barrier stay in flight through it.
__global__ __launch_bounds__(512, 1) void qkv_gemm(
    const float* __restrict__ x, const bf16* __restrict__ Wt,
    const float* __restrict__ bias_all,
    bf16* __restrict__ Qw, bf16* __restrict__ Kw, f16* __restrict__ Vtw) {
  __shared__ bf16 As[2][64 * 64];    // [m][k] swizzled, 8 KB each
  __shared__ bf16 Bs[2][384 * 64];   // [proj*128+n][k] swizzled, 48 KB each
  const int t = threadIdx.x;
  const int w = t >> 6;
  const int lane = t & 63;
  const int l31 = lane & 31;
  const int hi = lane >> 5;
  const int m0 = blockIdx.x * 64;
  const int m_off = (w & 1) * 32;
  const int n_off = ((w >> 1) & 3) * 32;

  const f32x16 z16 = {0.f,0.f,0.f,0.f,0.f,0.f,0.f,0.f,0.f,0.f,0.f,0.f,0.f,0.f,0.f,0.f};
  f32x16 acc[3];
  acc[0] = z16; acc[1] = z16; acc[2] = z16;

  // staging geometry: 512 thr -> row = t>>3 (0..63), granule g = t&7 (8 elems = 16 B)
  const int srow = t >> 3;
  const int g = t & 7;
  const int sgoff = (g ^ (srow & 7)) * 8;   // swizzled granule (write side)
  const int scol = g * 8;                   // global column base

  float4 xa[2];
  bf16x8 wa[6];
  {
    const float* p = &x[(size_t)(m0 + srow) * CDIM + scol];
    xa[0] = *(const float4*)p;
    xa[1] = *(const float4*)(p + 4);
  }
#pragma unroll
  for (int c = 0; c < 6; c++)
    wa[c] = *(const bf16x8*)&Wt[(size_t)(c * 64 + srow) * CDIM + scol];

  for (int kc = 0; kc < 16; kc++) {
    bf16* Ab = As[kc & 1];
    bf16* Bb = Bs[kc & 1];
    {
      bf16x8 v;
      v[0] = (bf16)xa[0].x; v[1] = (bf16)xa[0].y;
      v[2] = (bf16)xa[0].z; v[3] = (bf16)xa[0].w;
      v[4] = (bf16)xa[1].x; v[5] = (bf16)xa[1].y;
      v[6] = (bf16)xa[1].z; v[7] = (bf16)xa[1].w;
      *(bf16x8*)&Ab[srow * 64 + sgoff] = v;
    }
#pragma unroll
    for (int c = 0; c < 6; c++)
      *(bf16x8*)&Bb[(c * 64 + srow) * 64 + sgoff] = wa[c];

    const int kn = (kc < 15 ? kc + 1 : 15) * 64;   // clamped prefetch
    {
      const float* p = &x[(size_t)(m0 + srow) * CDIM + kn + scol];
      xa[0] = *(const float4*)p;
      xa[1] = *(const float4*)(p + 4);
    }
#pragma unroll
    for (int c = 0; c < 6; c++)
      wa[c] = *(const bf16x8*)&Wt[(size_t)(c * 64 + srow) * CDIM + kn + scol];

    lds_barrier();   // LDS writes visible; global loads remain in flight

#pragma unroll
    for (int ks = 0; ks < 4; ks++) {
      const int rg = ((ks * 2 + hi) ^ (l31 & 7)) * 8;   // swizzled read granule
      bf16x8 af = *(const bf16x8*)&Ab[(m_off + l31) * 64 + rg];
#pragma unroll
      for (int p = 0; p < 3; p++) {
        bf16x8 bfr = *(const bf16x8*)&Bb[(p * 128 + n_off + l31) * 64 + rg];
        acc[p] = __builtin_amdgcn_mfma_f32_32x32x16_bf16(af, bfr, acc[p], 0, 0, 0);
      }
    }
  }

  const int n = n_off + l31;
#pragma unroll
  for (int p = 0; p < 3; p++) {
    const float bias = bias_all[p * 128 + n];
    if (p < 2) {
      bf16* outp = (p == 0) ? Qw : Kw;
#pragma unroll
      for (int r = 0; r < 16; r++) {
        int m = m0 + m_off + (r & 3) + 8 * (r >> 2) + 4 * hi;
        outp[(size_t)m * DDIM + n] = (bf16)(acc[p][r] + bias);
      }
    } else {
#pragma unroll
      for (int gq = 0; gq < 4; gq++) {
        int mbase = m0 + m_off + 8 * gq + 4 * hi;
        f16x4 pv;
#pragma unroll
        for (int r = 0; r < 4; r++) pv[r] = (f16)(acc[p][gq * 4 + r] + bias);
        *(f16x4*)&Vtw[(size_t)n * LQ + mbase] = pv;
      }
    }
  }
}

// ---------------- K2: flash attention, 32x32 MFMA path ----------------------
// grid (128 q-blocks of 128 rows, 4 KV quarters), 256 thr (4 waves x 32 q rows).
// S^T = K·Q^T via 32x32x16 bf16; P -> PV A-frag via cvt_pkrtz + permlane32_swap;
// PV via full-rate 32x32x16 f16. No-drain lds_barrier (only change vs round 2).
__global__ __launch_bounds__(256, 2) void flash_kernel(
    const bf16* __restrict__ Qw, const bf16* __restrict__ Kw, const f16* __restrict__ Vtw,
    bf16* __restrict__ Opb, float* __restrict__ lp) {
  __shared__ bf16 Kl[2][64 * 136];    // [kv][d] pad 128->136
  __shared__ f16  Vl[2][128 * 72];    // [d][kv] pad 64->72

  const int t = threadIdx.x;
  const int w = t >> 6;
  const int lane = t & 63;
  const int l31 = lane & 31;
  const int hi = lane >> 5;
  // 512 blocks, bijective XCD chunk map: q-blocks sharing a KV panel co-reside per XCD
  const int lin = blockIdx.y * 128 + blockIdx.x;
  const int logical = ((lin & 7) << 6) + (lin >> 3);
  const int qb = logical & 127;       // 0..127
  const int sp = logical >> 7;        // 0..3
  const int batch = qb >> 5;
  const int q0w = qb * 128 + w * 32;
  const int kv_base = batch * 4096 + sp * 1024;

  // Q fragments (B-operand of S^T, 32x32x16): col=q=l31, k = ks*16 + hi*8 + j
  bf16x8 qf[8];
#pragma unroll
  for (int ks = 0; ks < 8; ks++)
    qf[ks] = *(const bf16x8*)&Qw[(size_t)(q0w + l31) * DDIM + ks * 16 + hi * 8];

  const f32x16 z16 = {0.f,0.f,0.f,0.f,0.f,0.f,0.f,0.f,0.f,0.f,0.f,0.f,0.f,0.f,0.f,0.f};
  f32x16 o[4];                        // O: row q=crow(r,hi), col d=dt*32+l31
  o[0] = z16; o[1] = z16; o[2] = z16; o[3] = z16;
  f32x16 liacc = z16;                 // row sums, row q=crow(r,hi)

  f16x8 ones;
#pragma unroll
  for (int i = 0; i < 8; i++) ones[i] = (f16)1.f;

  const int kr = t >> 4;              // 0..15 (+c*16)
  const int kcol = (t & 15) << 3;
  const int vr = t >> 3;              // 0..31 (+c*32)
  const int vcol = (t & 7) << 3;

  bf16x8 ka[4];
  f16x8 va[4];
#pragma unroll
  for (int c = 0; c < 4; c++)
    ka[c] = *(const bf16x8*)&Kw[(size_t)(kv_base + c * 16 + kr) * DDIM + kcol];
#pragma unroll
  for (int c = 0; c < 4; c++)
    va[c] = *(const f16x8*)&Vtw[(size_t)(c * 32 + vr) * LQ + kv_base + vcol];

  for (int tile = 0; tile < 16; tile++) {
    bf16* Kb = Kl[tile & 1];
    f16*  Vb = Vl[tile & 1];
#pragma unroll
    for (int c = 0; c < 4; c++)
      *(bf16x8*)&Kb[(c * 16 + kr) * 136 + kcol] = ka[c];
#pragma unroll
    for (int c = 0; c < 4; c++)
      *(f16x8*)&Vb[(c * 32 + vr) * 72 + vcol] = va[c];

    const int kvn = kv_base + (tile < 15 ? tile + 1 : 15) * 64;  // clamped prefetch
#pragma unroll
    for (int c = 0; c < 4; c++)
      ka[c] = *(const bf16x8*)&Kw[(size_t)(kvn + c * 16 + kr) * DDIM + kcol];
#pragma unroll
    for (int c = 0; c < 4; c++)
      va[c] = *(const f16x8*)&Vtw[(size_t)(c * 32 + vr) * LQ + kvn + vcol];

    lds_barrier();   // LDS writes visible; K/V global loads remain in flight

    // S^T = K·Q^T : sv_mk element (kv = mk*32 + (r&3)+8*(r>>2)+4*hi, q = l31)
    f32x16 sv0 = z16, sv1 = z16;
    __builtin_amdgcn_s_setprio(1);
#pragma unroll
    for (int ks = 0; ks < 8; ks++) {
      bf16x8 kf0 = *(const bf16x8*)&Kb[l31 * 136 + ks * 16 + hi * 8];
      bf16x8 kf1 = *(const bf16x8*)&Kb[(32 + l31) * 136 + ks * 16 + hi * 8];
      sv0 = __builtin_amdgcn_mfma_f32_32x32x16_bf16(kf0, qf[ks], sv0, 0, 0, 0);
      sv1 = __builtin_amdgcn_mfma_f32_32x32x16_bf16(kf1, qf[ks], sv1, 0, 0, 0);
    }
    __builtin_amdgcn_s_setprio(0);

    // P = exp2(S) — no max subtraction (scores O(1) by construction)
#pragma unroll
    for (int r = 0; r < 16; r++) {
      sv0[r] = __builtin_amdgcn_exp2f(sv0[r]);
      sv1[r] = __builtin_amdgcn_exp2f(sv1[r]);
    }

    // P^T(kv,q) -> PV A-frag (row=q=l31, k=kv): pack pairs, permlane32_swap.
#pragma unroll
    for (int mk = 0; mk < 2; mk++) {
      const f32x16 s = mk ? sv1 : sv0;
#pragma unroll
      for (int h = 0; h < 2; h++) {     // K=16 half within the 32-kv block
        const int b = h * 8;
        uint32_t a0 = pkrtz(s[b + 0], s[b + 1]);   // kv base+4hi+{0,1}
        uint32_t a1 = pkrtz(s[b + 2], s[b + 3]);   // kv base+4hi+{2,3}
        uint32_t a2 = pkrtz(s[b + 4], s[b + 5]);   // kv base+8+4hi+{0,1}
        uint32_t a3 = pkrtz(s[b + 6], s[b + 7]);   // kv base+8+4hi+{2,3}
        asm("v_permlane32_swap_b32 %0, %1" : "+v"(a0), "+v"(a2));  // a0->w0, a2->w2
        asm("v_permlane32_swap_b32 %0, %1" : "+v"(a1), "+v"(a3));  // a1->w1, a3->w3
        u32x4 aw; aw.x = a0; aw.y = a1; aw.z = a2; aw.w = a3;
        f16x8 pa = __builtin_bit_cast(f16x8, aw);  // A[q=l31][k=8hi+j]
        __builtin_amdgcn_s_setprio(1);
#pragma unroll
        for (int dt = 0; dt < 4; dt++) {
          f16x8 vf = *(const f16x8*)&Vb[(dt * 32 + l31) * 72 + mk * 32 + h * 16 + hi * 8];
          o[dt] = __builtin_amdgcn_mfma_f32_32x32x16_f16(pa, vf, o[dt], 0, 0, 0);
        }
        liacc = __builtin_amdgcn_mfma_f32_32x32x16_f16(pa, ones, liacc, 0, 0, 0);
        __builtin_amdgcn_s_setprio(0);
      }
    }
  }

  // epilogue: unnormalized O (bf16) + row sums l
  const size_t po = (size_t)sp * LQ * DDIM;
#pragma unroll
  for (int dt = 0; dt < 4; dt++)
#pragma unroll
    for (int r = 0; r < 16; r++) {
      int q = q0w + (r & 3) + 8 * (r >> 2) + 4 * hi;
      Opb[po + (size_t)q * DDIM + dt * 32 + l31] = (bf16)o[dt][r];
    }
  if (l31 == 0) {
#pragma unroll
    for (int r = 0; r < 16; r++)
      lp[(size_t)sp * LQ + q0w + (r & 3) + 8 * (r >> 2) + 4 * hi] = liacc[r];
  }
}

// ---------------- K3: combine: out = (sum O_sp) / (sum l_sp) ----------------
__global__ void combine_kernel(const bf16* __restrict__ Opb, const float* __restrict__ lp,
                               float* __restrict__ out) {
  int idx = blockIdx.x * 256 + threadIdx.x;   // LQ * 32
  int q = idx >> 5;
  int d = (idx & 31) * 4;
  float lsum = 0.f;
  float acc[4] = {0.f, 0.f, 0.f, 0.f};
#pragma unroll
  for (int sp = 0; sp < NSPLIT; sp++) {
    lsum += lp[(size_t)sp * LQ + q];
    bf16x4 ov = *(const bf16x4*)&Opb[(size_t)sp * LQ * DDIM + (size_t)q * DDIM + d];
#pragma unroll
    for (int j = 0; j < 4; j++) acc[j] += (float)ov[j];
  }
  float inv = 1.0f / lsum;
  float4 r;
  r.x = acc[0] * inv; r.y = acc[1] * inv; r.z = acc[2] * inv; r.w = acc[3] * inv;
  *(float4*)&out[(size_t)q * DDIM + d] = r;
}

extern "C" void kernel_launch(void* const* d_in, const int* in_sizes, int n_in,
                              void* d_out, int out_size, void* d_ws, size_t ws_size,
                              hipStream_t stream) {
  const float* x  = (const float*)d_in[0];
  const float* Wq = (const float*)d_in[1];
  const float* bq = (const float*)d_in[2];
  const float* Wk = (const float*)d_in[3];
  const float* bk = (const float*)d_in[4];
  const float* Wv = (const float*)d_in[5];
  const float* bv = (const float*)d_in[6];
  char* ws = (char*)d_ws;
  bf16* Qw   = (bf16*)(ws);                              // 4 MB (prescaled by QS)
  bf16* Kw   = (bf16*)(ws + ((size_t)4 << 20));          // 4 MB
  f16*  Vtw  = (f16*)(ws + ((size_t)8 << 20));           // 4 MB (transposed [d][q], f16)
  bf16* Wt   = (bf16*)(ws + ((size_t)12 << 20));         // 768 KB
  float* bias_all = (float*)(ws + ((size_t)12 << 20) + 786432); // 1.5 KB
  bf16* Opb  = (bf16*)(ws + ((size_t)13 << 20));         // 16 MB (4 splits, bf16)
  float* lpp = (float*)(ws + ((size_t)29 << 20));        // 256 KB
  float* out = (float*)d_out;

  prep_kernel<<<1536, 256, 0, stream>>>(Wq, Wk, Wv, bq, bk, bv, Wt, bias_all);
  qkv_gemm<<<256, 512, 0, stream>>>(x, Wt, bias_all, Qw, Kw, Vtw);
  flash_kernel<<<dim3(128, NSPLIT), 256, 0, stream>>>(Qw, Kw, Vtw, Opb, lpp);
  combine_kernel<<<2048, 256, 0, stream>>>(Opb, lpp, out);
}

// Round 6
// 169.285 us; speedup vs baseline: 1.0911x; 1.0113x over previous
//
#include <hip/hip_runtime.h>
#include <stdint.h>

typedef __bf16 bf16;
typedef __bf16 bf16x8 __attribute__((ext_vector_type(8)));
typedef __bf16 bf16x4 __attribute__((ext_vector_type(4)));
typedef _Float16 f16;
typedef f16 f16x8 __attribute__((ext_vector_type(8)));
typedef f16 f16x4 __attribute__((ext_vector_type(4)));
typedef float f32x4 __attribute__((ext_vector_type(4)));
typedef float f32x16 __attribute__((ext_vector_type(16)));
typedef uint32_t u32x4 __attribute__((ext_vector_type(4)));

#define LQ    16384   // B*L total rows
#define CDIM  1024
#define DDIM  128
#define NSPLIT 4
#define QS 0.12751741f   // (1/sqrt(128)) * log2(e): folded into Q -> softmax uses exp2

static __device__ __forceinline__ uint32_t pkrtz(float a, float b) {
  return __builtin_bit_cast(uint32_t, __builtin_amdgcn_cvt_pkrtz(a, b));
}

// no-drain barrier: LDS visibility only; global loads stay in flight (reg-staged,
// so vmcnt is a private register dependency the compiler tracks with counted waits).
static __device__ __forceinline__ void lds_barrier() {
  asm volatile("s_waitcnt lgkmcnt(0)" ::: "memory");
  __builtin_amdgcn_s_barrier();
}

// ---------------- K0: Wt[3][128][1024] (bf16, Q rows prescaled) + bias_all[384]
__global__ void prep_kernel(const float* __restrict__ Wq, const float* __restrict__ Wk,
                            const float* __restrict__ Wv, const float* __restrict__ bq,
                            const float* __restrict__ bk, const float* __restrict__ bv,
                            bf16* __restrict__ Wt, float* __restrict__ bias_all) {
  int idx = blockIdx.x * 256 + threadIdx.x;      // 0 .. 3*131072
  int p = idx >> 17;
  int rem = idx & 131071;
  int k = rem >> 7, n = rem & 127;
  const float* W = (p == 0) ? Wq : (p == 1) ? Wk : Wv;
  float s = (p == 0) ? QS : 1.0f;
  Wt[(size_t)(p * 128 + n) * CDIM + k] = (bf16)(W[rem] * s);
  if (idx < 384) {
    int pp = idx >> 7, nn = idx & 127;
    const float* b = (pp == 0) ? bq : (pp == 1) ? bk : bv;
    bias_all[idx] = b[nn] * ((pp == 0) ? QS : 1.0f);
  }
}

// ---------------- K1: QKV GEMM, BM=64, BN=384 (all 3 projections per block) --
// grid 256 = 1 block/CU, 512 thr (8 waves, 2m x 4n), wave tile 32x32 x 3 proj.
// x read ONCE total; W L2-resident. LDS 112 KB dbuf, XOR-swizzled granules.
// No-drain lds_barrier: loads issued pre-barrier stay in flight through it.
__global__ __launch_bounds__(512, 1) void qkv_gemm(
    const float* __restrict__ x, const bf16* __restrict__ Wt,
    const float* __restrict__ bias_all,
    bf16* __restrict__ Qw, bf16* __restrict__ Kw, f16* __restrict__ Vtw) {
  __shared__ bf16 As[2][64 * 64];    // [m][k] swizzled, 8 KB each
  __shared__ bf16 Bs[2][384 * 64];   // [proj*128+n][k] swizzled, 48 KB each
  const int t = threadIdx.x;
  const int w = t >> 6;
  const int lane = t & 63;
  const int l31 = lane & 31;
  const int hi = lane >> 5;
  const int m0 = blockIdx.x * 64;
  const int m_off = (w & 1) * 32;
  const int n_off = ((w >> 1) & 3) * 32;

  const f32x16 z16 = {0.f,0.f,0.f,0.f,0.f,0.f,0.f,0.f,0.f,0.f,0.f,0.f,0.f,0.f,0.f,0.f};
  f32x16 acc[3];
  acc[0] = z16; acc[1] = z16; acc[2] = z16;

  // staging geometry: 512 thr -> row = t>>3 (0..63), granule g = t&7 (8 elems = 16 B)
  const int srow = t >> 3;
  const int g = t & 7;
  const int sgoff = (g ^ (srow & 7)) * 8;   // swizzled granule (write side)
  const int scol = g * 8;                   // global column base

  float4 xa[2];
  bf16x8 wa[6];
  {
    const float* p = &x[(size_t)(m0 + srow) * CDIM + scol];
    xa[0] = *(const float4*)p;
    xa[1] = *(const float4*)(p + 4);
  }
#pragma unroll
  for (int c = 0; c < 6; c++)
    wa[c] = *(const bf16x8*)&Wt[(size_t)(c * 64 + srow) * CDIM + scol];

  for (int kc = 0; kc < 16; kc++) {
    bf16* Ab = As[kc & 1];
    bf16* Bb = Bs[kc & 1];
    {
      bf16x8 v;
      v[0] = (bf16)xa[0].x; v[1] = (bf16)xa[0].y;
      v[2] = (bf16)xa[0].z; v[3] = (bf16)xa[0].w;
      v[4] = (bf16)xa[1].x; v[5] = (bf16)xa[1].y;
      v[6] = (bf16)xa[1].z; v[7] = (bf16)xa[1].w;
      *(bf16x8*)&Ab[srow * 64 + sgoff] = v;
    }
#pragma unroll
    for (int c = 0; c < 6; c++)
      *(bf16x8*)&Bb[(c * 64 + srow) * 64 + sgoff] = wa[c];

    const int kn = (kc < 15 ? kc + 1 : 15) * 64;   // clamped prefetch
    {
      const float* p = &x[(size_t)(m0 + srow) * CDIM + kn + scol];
      xa[0] = *(const float4*)p;
      xa[1] = *(const float4*)(p + 4);
    }
#pragma unroll
    for (int c = 0; c < 6; c++)
      wa[c] = *(const bf16x8*)&Wt[(size_t)(c * 64 + srow) * CDIM + kn + scol];

    lds_barrier();   // LDS writes visible; global loads remain in flight

#pragma unroll
    for (int ks = 0; ks < 4; ks++) {
      const int rg = ((ks * 2 + hi) ^ (l31 & 7)) * 8;   // swizzled read granule
      bf16x8 af = *(const bf16x8*)&Ab[(m_off + l31) * 64 + rg];
#pragma unroll
      for (int p = 0; p < 3; p++) {
        bf16x8 bfr = *(const bf16x8*)&Bb[(p * 128 + n_off + l31) * 64 + rg];
        acc[p] = __builtin_amdgcn_mfma_f32_32x32x16_bf16(af, bfr, acc[p], 0, 0, 0);
      }
    }
  }

  const int n = n_off + l31;
#pragma unroll
  for (int p = 0; p < 3; p++) {
    const float bias = bias_all[p * 128 + n];
    if (p < 2) {
      bf16* outp = (p == 0) ? Qw : Kw;
#pragma unroll
      for (int r = 0; r < 16; r++) {
        int m = m0 + m_off + (r & 3) + 8 * (r >> 2) + 4 * hi;
        outp[(size_t)m * DDIM + n] = (bf16)(acc[p][r] + bias);
      }
    } else {
#pragma unroll
      for (int gq = 0; gq < 4; gq++) {
        int mbase = m0 + m_off + 8 * gq + 4 * hi;
        f16x4 pv;
#pragma unroll
        for (int r = 0; r < 4; r++) pv[r] = (f16)(acc[p][gq * 4 + r] + bias);
        *(f16x4*)&Vtw[(size_t)n * LQ + mbase] = pv;
      }
    }
  }
}

// ---------------- K2: flash attention, pipelined 32x32 MFMA path ------------
// grid (128 q-blocks of 128 rows, 4 KV quarters), 256 thr (4 waves x 32 q rows).
// Cross-tile software pipeline (T15): per iteration the ZIP region interleaves
// S^T(t+1) (bf16 MFMA, Kb[(t+1)&1]) with PV(t)+li(t) (f16 MFMA, Vb[t&1], pa(t)).
// Both are pure-MFMA and independent -> one pipe-fed region instead of two
// serial phases; exp2(t+1)/pack(t+1) then overlap the other wave's ZIP.
__global__ __launch_bounds__(256, 2) void flash_kernel(
    const bf16* __restrict__ Qw, const bf16* __restrict__ Kw, const f16* __restrict__ Vtw,
    bf16* __restrict__ Opb, float* __restrict__ lp) {
  __shared__ bf16 Kl[2][64 * 136];    // [kv][d] pad 128->136
  __shared__ f16  Vl[2][128 * 72];    // [d][kv] pad 64->72

  const int t = threadIdx.x;
  const int w = t >> 6;
  const int lane = t & 63;
  const int l31 = lane & 31;
  const int hi = lane >> 5;
  // 512 blocks, bijective XCD chunk map: q-blocks sharing a KV panel co-reside per XCD
  const int lin = blockIdx.y * 128 + blockIdx.x;
  const int logical = ((lin & 7) << 6) + (lin >> 3);
  const int qb = logical & 127;       // 0..127
  const int sp = logical >> 7;        // 0..3
  const int batch = qb >> 5;
  const int q0w = qb * 128 + w * 32;
  const int kv_base = batch * 4096 + sp * 1024;

  // Q fragments (B-operand of S^T, 32x32x16): col=q=l31, k = ks*16 + hi*8 + j
  bf16x8 qf[8];
#pragma unroll
  for (int ks = 0; ks < 8; ks++)
    qf[ks] = *(const bf16x8*)&Qw[(size_t)(q0w + l31) * DDIM + ks * 16 + hi * 8];

  const f32x16 z16 = {0.f,0.f,0.f,0.f,0.f,0.f,0.f,0.f,0.f,0.f,0.f,0.f,0.f,0.f,0.f,0.f};
  f32x16 o[4];                        // O: row q=crow(r,hi), col d=dt*32+l31
  o[0] = z16; o[1] = z16; o[2] = z16; o[3] = z16;
  f32x16 liacc = z16;                 // row sums, row q=crow(r,hi)

  f16x8 ones;
#pragma unroll
  for (int i = 0; i < 8; i++) ones[i] = (f16)1.f;

  const int kr = t >> 4;              // 0..15 (+c*16)
  const int kcol = (t & 15) << 3;
  const int vr = t >> 3;              // 0..31 (+c*32)
  const int vcol = (t & 7) << 3;

  bf16x8 ka[4];
  f16x8 va[4];
  // packed P of the previous tile: pa[slice], slice = mk*2+h, A[q=l31][k=8hi+j]
  f16x8 pa[4];

  // ---- prologue: stage tile 0, load tile 1, S^T(0), exp2, pack ----
#pragma unroll
  for (int c = 0; c < 4; c++)
    ka[c] = *(const bf16x8*)&Kw[(size_t)(kv_base + c * 16 + kr) * DDIM + kcol];
#pragma unroll
  for (int c = 0; c < 4; c++)
    va[c] = *(const f16x8*)&Vtw[(size_t)(c * 32 + vr) * LQ + kv_base + vcol];

#pragma unroll
  for (int c = 0; c < 4; c++)
    *(bf16x8*)&Kl[0][(c * 16 + kr) * 136 + kcol] = ka[c];
#pragma unroll
  for (int c = 0; c < 4; c++)
    *(f16x8*)&Vl[0][(c * 32 + vr) * 72 + vcol] = va[c];

#pragma unroll
  for (int c = 0; c < 4; c++)
    ka[c] = *(const bf16x8*)&Kw[(size_t)(kv_base + 64 + c * 16 + kr) * DDIM + kcol];
#pragma unroll
  for (int c = 0; c < 4; c++)
    va[c] = *(const f16x8*)&Vtw[(size_t)(c * 32 + vr) * LQ + kv_base + 64 + vcol];

  lds_barrier();

  f32x16 sv0 = z16, sv1 = z16;
  __builtin_amdgcn_s_setprio(1);
#pragma unroll
  for (int ks = 0; ks < 8; ks++) {
    bf16x8 kf0 = *(const bf16x8*)&Kl[0][l31 * 136 + ks * 16 + hi * 8];
    bf16x8 kf1 = *(const bf16x8*)&Kl[0][(32 + l31) * 136 + ks * 16 + hi * 8];
    sv0 = __builtin_amdgcn_mfma_f32_32x32x16_bf16(kf0, qf[ks], sv0, 0, 0, 0);
    sv1 = __builtin_amdgcn_mfma_f32_32x32x16_bf16(kf1, qf[ks], sv1, 0, 0, 0);
  }
  __builtin_amdgcn_s_setprio(0);
#pragma unroll
  for (int r = 0; r < 16; r++) {
    sv0[r] = __builtin_amdgcn_exp2f(sv0[r]);
    sv1[r] = __builtin_amdgcn_exp2f(sv1[r]);
  }
#pragma unroll
  for (int sl = 0; sl < 4; sl++) {    // slice = mk*2+h
    const int b = (sl & 1) * 8;
    float s0 = (sl >> 1) ? sv1[b + 0] : sv0[b + 0];
    float s1 = (sl >> 1) ? sv1[b + 1] : sv0[b + 1];
    float s2 = (sl >> 1) ? sv1[b + 2] : sv0[b + 2];
    float s3 = (sl >> 1) ? sv1[b + 3] : sv0[b + 3];
    float s4 = (sl >> 1) ? sv1[b + 4] : sv0[b + 4];
    float s5 = (sl >> 1) ? sv1[b + 5] : sv0[b + 5];
    float s6 = (sl >> 1) ? sv1[b + 6] : sv0[b + 6];
    float s7 = (sl >> 1) ? sv1[b + 7] : sv0[b + 7];
    uint32_t a0 = pkrtz(s0, s1);
    uint32_t a1 = pkrtz(s2, s3);
    uint32_t a2 = pkrtz(s4, s5);
    uint32_t a3 = pkrtz(s6, s7);
    asm("v_permlane32_swap_b32 %0, %1" : "+v"(a0), "+v"(a2));
    asm("v_permlane32_swap_b32 %0, %1" : "+v"(a1), "+v"(a3));
    u32x4 aw; aw.x = a0; aw.y = a1; aw.z = a2; aw.w = a3;
    pa[sl] = __builtin_bit_cast(f16x8, aw);
  }

  // ---- main pipeline: iter t computes S^T(t+1) ZIP PV(t) ----
  for (int tile = 0; tile < 15; tile++) {
    bf16* Kb = Kl[(tile + 1) & 1];
    f16*  Vb = Vl[(tile + 1) & 1];
    f16*  Vp = Vl[tile & 1];          // previous tile's V (PV operand)
#pragma unroll
    for (int c = 0; c < 4; c++)
      *(bf16x8*)&Kb[(c * 16 + kr) * 136 + kcol] = ka[c];
#pragma unroll
    for (int c = 0; c < 4; c++)
      *(f16x8*)&Vb[(c * 32 + vr) * 72 + vcol] = va[c];

    const int kvn = kv_base + (tile < 14 ? tile + 2 : 15) * 64;  // clamped prefetch
#pragma unroll
    for (int c = 0; c < 4; c++)
      ka[c] = *(const bf16x8*)&Kw[(size_t)(kvn + c * 16 + kr) * DDIM + kcol];
#pragma unroll
    for (int c = 0; c < 4; c++)
      va[c] = *(const f16x8*)&Vtw[(size_t)(c * 32 + vr) * LQ + kvn + vcol];

    lds_barrier();   // K/V(t+1) visible; prefetch loads stay in flight

    // ZIP: S^T(t+1) interleaved with PV(t) + li(t) — independent MFMA chains
    sv0 = z16; sv1 = z16;
    __builtin_amdgcn_s_setprio(1);
#pragma unroll
    for (int i = 0; i < 4; i++) {
      // S^T part: ks = 2i, 2i+1
      bf16x8 kf0a = *(const bf16x8*)&Kb[l31 * 136 + (2 * i) * 16 + hi * 8];
      bf16x8 kf1a = *(const bf16x8*)&Kb[(32 + l31) * 136 + (2 * i) * 16 + hi * 8];
      bf16x8 kf0b = *(const bf16x8*)&Kb[l31 * 136 + (2 * i + 1) * 16 + hi * 8];
      bf16x8 kf1b = *(const bf16x8*)&Kb[(32 + l31) * 136 + (2 * i + 1) * 16 + hi * 8];
      sv0 = __builtin_amdgcn_mfma_f32_32x32x16_bf16(kf0a, qf[2 * i], sv0, 0, 0, 0);
      sv1 = __builtin_amdgcn_mfma_f32_32x32x16_bf16(kf1a, qf[2 * i], sv1, 0, 0, 0);
      // PV part: slice i (mk = i>>1, h = i&1), operands from prev tile
      const int koff = (i >> 1) * 32 + (i & 1) * 16 + hi * 8;
#pragma unroll
      for (int dt = 0; dt < 4; dt++) {
        f16x8 vf = *(const f16x8*)&Vp[(dt * 32 + l31) * 72 + koff];
        o[dt] = __builtin_amdgcn_mfma_f32_32x32x16_f16(pa[i], vf, o[dt], 0, 0, 0);
      }
      liacc = __builtin_amdgcn_mfma_f32_32x32x16_f16(pa[i], ones, liacc, 0, 0, 0);
      sv0 = __builtin_amdgcn_mfma_f32_32x32x16_bf16(kf0b, qf[2 * i + 1], sv0, 0, 0, 0);
      sv1 = __builtin_amdgcn_mfma_f32_32x32x16_bf16(kf1b, qf[2 * i + 1], sv1, 0, 0, 0);
    }
    __builtin_amdgcn_s_setprio(0);

    // exp2(t+1) + pack(t+1) -> pa (VALU; overlaps other wave's ZIP)
#pragma unroll
    for (int r = 0; r < 16; r++) {
      sv0[r] = __builtin_amdgcn_exp2f(sv0[r]);
      sv1[r] = __builtin_amdgcn_exp2f(sv1[r]);
    }
#pragma unroll
    for (int sl = 0; sl < 4; sl++) {
      const int b = (sl & 1) * 8;
      float s0 = (sl >> 1) ? sv1[b + 0] : sv0[b + 0];
      float s1 = (sl >> 1) ? sv1[b + 1] : sv0[b + 1];
      float s2 = (sl >> 1) ? sv1[b + 2] : sv0[b + 2];
      float s3 = (sl >> 1) ? sv1[b + 3] : sv0[b + 3];
      float s4 = (sl >> 1) ? sv1[b + 4] : sv0[b + 4];
      float s5 = (sl >> 1) ? sv1[b + 5] : sv0[b + 5];
      float s6 = (sl >> 1) ? sv1[b + 6] : sv0[b + 6];
      float s7 = (sl >> 1) ? sv1[b + 7] : sv0[b + 7];
      uint32_t a0 = pkrtz(s0, s1);
      uint32_t a1 = pkrtz(s2, s3);
      uint32_t a2 = pkrtz(s4, s5);
      uint32_t a3 = pkrtz(s6, s7);
      asm("v_permlane32_swap_b32 %0, %1" : "+v"(a0), "+v"(a2));
      asm("v_permlane32_swap_b32 %0, %1" : "+v"(a1), "+v"(a3));
      u32x4 aw; aw.x = a0; aw.y = a1; aw.z = a2; aw.w = a3;
      pa[sl] = __builtin_bit_cast(f16x8, aw);
    }
  }

  // ---- epilogue: PV(15) ----
  {
    f16* Vp = Vl[15 & 1];
    __builtin_amdgcn_s_setprio(1);
#pragma unroll
    for (int i = 0; i < 4; i++) {
      const int koff = (i >> 1) * 32 + (i & 1) * 16 + hi * 8;
#pragma unroll
      for (int dt = 0; dt < 4; dt++) {
        f16x8 vf = *(const f16x8*)&Vp[(dt * 32 + l31) * 72 + koff];
        o[dt] = __builtin_amdgcn_mfma_f32_32x32x16_f16(pa[i], vf, o[dt], 0, 0, 0);
      }
      liacc = __builtin_amdgcn_mfma_f32_32x32x16_f16(pa[i], ones, liacc, 0, 0, 0);
    }
    __builtin_amdgcn_s_setprio(0);
  }

  // epilogue: unnormalized O (bf16) + row sums l
  const size_t po = (size_t)sp * LQ * DDIM;
#pragma unroll
  for (int dt = 0; dt < 4; dt++)
#pragma unroll
    for (int r = 0; r < 16; r++) {
      int q = q0w + (r & 3) + 8 * (r >> 2) + 4 * hi;
      Opb[po + (size_t)q * DDIM + dt * 32 + l31] = (bf16)o[dt][r];
    }
  if (l31 == 0) {
#pragma unroll
    for (int r = 0; r < 16; r++)
      lp[(size_t)sp * LQ + q0w + (r & 3) + 8 * (r >> 2) + 4 * hi] = liacc[r];
  }
}

// ---------------- K3: combine: out = (sum O_sp) / (sum l_sp) ----------------
__global__ void combine_kernel(const bf16* __restrict__ Opb, const float* __restrict__ lp,
                               float* __restrict__ out) {
  int idx = blockIdx.x * 256 + threadIdx.x;   // LQ * 32
  int q = idx >> 5;
  int d = (idx & 31) * 4;
  float lsum = 0.f;
  float acc[4] = {0.f, 0.f, 0.f, 0.f};
#pragma unroll
  for (int sp = 0; sp < NSPLIT; sp++) {
    lsum += lp[(size_t)sp * LQ + q];
    bf16x4 ov = *(const bf16x4*)&Opb[(size_t)sp * LQ * DDIM + (size_t)q * DDIM + d];
#pragma unroll
    for (int j = 0; j < 4; j++) acc[j] += (float)ov[j];
  }
  float inv = 1.0f / lsum;
  float4 r;
  r.x = acc[0] * inv; r.y = acc[1] * inv; r.z = acc[2] * inv; r.w = acc[3] * inv;
  *(float4*)&out[(size_t)q * DDIM + d] = r;
}

extern "C" void kernel_launch(void* const* d_in, const int* in_sizes, int n_in,
                              void* d_out, int out_size, void* d_ws, size_t ws_size,
                              hipStream_t stream) {
  const float* x  = (const float*)d_in[0];
  const float* Wq = (const float*)d_in[1];
  const float* bq = (const float*)d_in[2];
  const float* Wk = (const float*)d_in[3];
  const float* bk = (const float*)d_in[4];
  const float* Wv = (const float*)d_in[5];
  const float* bv = (const float*)d_in[6];
  char* ws = (char*)d_ws;
  bf16* Qw   = (bf16*)(ws);                              // 4 MB (prescaled by QS)
  bf16* Kw   = (bf16*)(ws + ((size_t)4 << 20));          // 4 MB
  f16*  Vtw  = (f16*)(ws + ((size_t)8 << 20));           // 4 MB (transposed [d][q], f16)
  bf16* Wt   = (bf16*)(ws + ((size_t)12 << 20));         // 768 KB
  float* bias_all = (float*)(ws + ((size_t)12 << 20) + 786432); // 1.5 KB
  bf16* Opb  = (bf16*)(ws + ((size_t)13 << 20));         // 16 MB (4 splits, bf16)
  float* lpp = (float*)(ws + ((size_t)29 << 20));        // 256 KB
  float* out = (float*)d_out;

  prep_kernel<<<1536, 256, 0, stream>>>(Wq, Wk, Wv, bq, bk, bv, Wt, bias_all);
  qkv_gemm<<<256, 512, 0, stream>>>(x, Wt, bias_all, Qw, Kw, Vtw);
  flash_kernel<<<dim3(128, NSPLIT), 256, 0, stream>>>(Qw, Kw, Vtw, Opb, lpp);
  combine_kernel<<<2048, 256, 0, stream>>>(Opb, lpp, out);
}

// Round 9
// 169.156 us; speedup vs baseline: 1.0920x; 1.0008x over previous
//
#include <hip/hip_runtime.h>
#include <stdint.h>

typedef __bf16 bf16;
typedef __bf16 bf16x8 __attribute__((ext_vector_type(8)));
typedef __bf16 bf16x4 __attribute__((ext_vector_type(4)));
typedef _Float16 f16;
typedef f16 f16x8 __attribute__((ext_vector_type(8)));
typedef f16 f16x4 __attribute__((ext_vector_type(4)));
typedef float f32x4 __attribute__((ext_vector_type(4)));
typedef float f32x16 __attribute__((ext_vector_type(16)));
typedef uint32_t u32x4 __attribute__((ext_vector_type(4)));

#define LQ    16384   // B*L total rows
#define CDIM  1024
#define DDIM  128
#define NSPLIT 4
#define QS 0.12751741f   // (1/sqrt(128)) * log2(e): folded into Q -> softmax uses exp2

static __device__ __forceinline__ uint32_t pkrtz(float a, float b) {
  return __builtin_bit_cast(uint32_t, __builtin_amdgcn_cvt_pkrtz(a, b));
}

// no-drain barrier: LDS visibility only; global loads stay in flight (reg-staged,
// so vmcnt is a private register dependency the compiler tracks with counted waits).
static __device__ __forceinline__ void lds_barrier() {
  asm volatile("s_waitcnt lgkmcnt(0)" ::: "memory");
  __builtin_amdgcn_s_barrier();
}

// ---------------- K0: Wt[3][128][1024] (bf16, Q rows prescaled) + bias_all[384]
__global__ void prep_kernel(const float* __restrict__ Wq, const float* __restrict__ Wk,
                            const float* __restrict__ Wv, const float* __restrict__ bq,
                            const float* __restrict__ bk, const float* __restrict__ bv,
                            bf16* __restrict__ Wt, float* __restrict__ bias_all) {
  int idx = blockIdx.x * 256 + threadIdx.x;      // 0 .. 3*131072
  int p = idx >> 17;
  int rem = idx & 131071;
  int k = rem >> 7, n = rem & 127;
  const float* W = (p == 0) ? Wq : (p == 1) ? Wk : Wv;
  float s = (p == 0) ? QS : 1.0f;
  Wt[(size_t)(p * 128 + n) * CDIM + k] = (bf16)(W[rem] * s);
  if (idx < 384) {
    int pp = idx >> 7, nn = idx & 127;
    const float* b = (pp == 0) ? bq : (pp == 1) ? bk : bv;
    bias_all[idx] = b[nn] * ((pp == 0) ? QS : 1.0f);
  }
}

// ---------------- K1: QKV GEMM, BM=64, BN=384 (all 3 projections per block) --
// grid 256 = 1 block/CU, 512 thr (8 waves, 2m x 4n), wave tile 32x32 x 3 proj.
// x read ONCE total; W L2-resident. LDS 112 KB dbuf, XOR-swizzled granules.
// No-drain lds_barrier: loads issued pre-barrier stay in flight through it.
__global__ __launch_bounds__(512, 1) void qkv_gemm(
    const float* __restrict__ x, const bf16* __restrict__ Wt,
    const float* __restrict__ bias_all,
    bf16* __restrict__ Qw, bf16* __restrict__ Kw, f16* __restrict__ Vtw) {
  __shared__ bf16 As[2][64 * 64];    // [m][k] swizzled, 8 KB each
  __shared__ bf16 Bs[2][384 * 64];   // [proj*128+n][k] swizzled, 48 KB each
  const int t = threadIdx.x;
  const int w = t >> 6;
  const int lane = t & 63;
  const int l31 = lane & 31;
  const int hi = lane >> 5;
  const int m0 = blockIdx.x * 64;
  const int m_off = (w & 1) * 32;
  const int n_off = ((w >> 1) & 3) * 32;

  const f32x16 z16 = {0.f,0.f,0.f,0.f,0.f,0.f,0.f,0.f,0.f,0.f,0.f,0.f,0.f,0.f,0.f,0.f};
  f32x16 acc[3];
  acc[0] = z16; acc[1] = z16; acc[2] = z16;

  // staging geometry: 512 thr -> row = t>>3 (0..63), granule g = t&7 (8 elems = 16 B)
  const int srow = t >> 3;
  const int g = t & 7;
  const int sgoff = (g ^ (srow & 7)) * 8;   // swizzled granule (write side)
  const int scol = g * 8;                   // global column base

  float4 xa[2];
  bf16x8 wa[6];
  {
    const float* p = &x[(size_t)(m0 + srow) * CDIM + scol];
    xa[0] = *(const float4*)p;
    xa[1] = *(const float4*)(p + 4);
  }
#pragma unroll
  for (int c = 0; c < 6; c++)
    wa[c] = *(const bf16x8*)&Wt[(size_t)(c * 64 + srow) * CDIM + scol];

  for (int kc = 0; kc < 16; kc++) {
    bf16* Ab = As[kc & 1];
    bf16* Bb = Bs[kc & 1];
    {
      bf16x8 v;
      v[0] = (bf16)xa[0].x; v[1] = (bf16)xa[0].y;
      v[2] = (bf16)xa[0].z; v[3] = (bf16)xa[0].w;
      v[4] = (bf16)xa[1].x; v[5] = (bf16)xa[1].y;
      v[6] = (bf16)xa[1].z; v[7] = (bf16)xa[1].w;
      *(bf16x8*)&Ab[srow * 64 + sgoff] = v;
    }
#pragma unroll
    for (int c = 0; c < 6; c++)
      *(bf16x8*)&Bb[(c * 64 + srow) * 64 + sgoff] = wa[c];

    const int kn = (kc < 15 ? kc + 1 : 15) * 64;   // clamped prefetch
    {
      const float* p = &x[(size_t)(m0 + srow) * CDIM + kn + scol];
      xa[0] = *(const float4*)p;
      xa[1] = *(const float4*)(p + 4);
    }
#pragma unroll
    for (int c = 0; c < 6; c++)
      wa[c] = *(const bf16x8*)&Wt[(size_t)(c * 64 + srow) * CDIM + kn + scol];

    lds_barrier();   // LDS writes visible; global loads remain in flight

#pragma unroll
    for (int ks = 0; ks < 4; ks++) {
      const int rg = ((ks * 2 + hi) ^ (l31 & 7)) * 8;   // swizzled read granule
      bf16x8 af = *(const bf16x8*)&Ab[(m_off + l31) * 64 + rg];
#pragma unroll
      for (int p = 0; p < 3; p++) {
        bf16x8 bfr = *(const bf16x8*)&Bb[(p * 128 + n_off + l31) * 64 + rg];
        acc[p] = __builtin_amdgcn_mfma_f32_32x32x16_bf16(af, bfr, acc[p], 0, 0, 0);
      }
    }
    __builtin_amdgcn_s_barrier();   // reads of buf done before next-iter writes
  }

  const int n = n_off + l31;
#pragma unroll
  for (int p = 0; p < 3; p++) {
    const float bias = bias_all[p * 128 + n];
    if (p < 2) {
      bf16* outp = (p == 0) ? Qw : Kw;
#pragma unroll
      for (int r = 0; r < 16; r++) {
        int m = m0 + m_off + (r & 3) + 8 * (r >> 2) + 4 * hi;
        outp[(size_t)m * DDIM + n] = (bf16)(acc[p][r] + bias);
      }
    } else {
#pragma unroll
      for (int gq = 0; gq < 4; gq++) {
        int mbase = m0 + m_off + 8 * gq + 4 * hi;
        f16x4 pv;
#pragma unroll
        for (int r = 0; r < 4; r++) pv[r] = (f16)(acc[p][gq * 4 + r] + bias);
        *(f16x4*)&Vtw[(size_t)n * LQ + mbase] = pv;
      }
    }
  }
}

// ---------------- K2: flash attention, pipelined 32x32 MFMA path ------------
// grid (128 q-blocks of 128 rows, 4 KV quarters), 256 thr (4 waves x 32 q rows).
// Round-6 compute (verified green) + RACE FIX: an end-of-body s_barrier
// separates iter-t's ZIP reads of Vl[t&1] from iter-(t+1)'s staging writes to
// the same buffer (previously only the mid-iteration barrier existed, which
// does NOT order them -> latent flaky corruption). All of a wave's LDS reads
// are complete at that barrier (every consumer MFMA precedes it), so no
// lgkmcnt(0) is needed. K was already safe (re-write 2 barriers downstream).
__global__ __launch_bounds__(256, 2) void flash_kernel(
    const bf16* __restrict__ Qw, const bf16* __restrict__ Kw, const f16* __restrict__ Vtw,
    bf16* __restrict__ Opb, float* __restrict__ lp) {
  __shared__ bf16 Kl[2][64 * 136];    // [kv][d] pad 128->136
  __shared__ f16  Vl[2][128 * 72];    // [d][kv] pad 64->72

  const int t = threadIdx.x;
  const int w = t >> 6;
  const int lane = t & 63;
  const int l31 = lane & 31;
  const int hi = lane >> 5;
  // 512 blocks, bijective XCD chunk map: q-blocks sharing a KV panel co-reside per XCD
  const int lin = blockIdx.y * 128 + blockIdx.x;
  const int logical = ((lin & 7) << 6) + (lin >> 3);
  const int qb = logical & 127;       // 0..127
  const int sp = logical >> 7;        // 0..3
  const int batch = qb >> 5;
  const int q0w = qb * 128 + w * 32;
  const int kv_base = batch * 4096 + sp * 1024;

  // Q fragments (B-operand of S^T, 32x32x16): col=q=l31, k = ks*16 + hi*8 + j
  bf16x8 qf[8];
#pragma unroll
  for (int ks = 0; ks < 8; ks++)
    qf[ks] = *(const bf16x8*)&Qw[(size_t)(q0w + l31) * DDIM + ks * 16 + hi * 8];

  const f32x16 z16 = {0.f,0.f,0.f,0.f,0.f,0.f,0.f,0.f,0.f,0.f,0.f,0.f,0.f,0.f,0.f,0.f};
  f32x16 o[4];                        // O: row q=crow(r,hi), col d=dt*32+l31
  o[0] = z16; o[1] = z16; o[2] = z16; o[3] = z16;
  f32x16 liacc = z16;                 // row sums, row q=crow(r,hi)

  f16x8 ones;
#pragma unroll
  for (int i = 0; i < 8; i++) ones[i] = (f16)1.f;

  const int kr = t >> 4;              // 0..15 (+c*16)
  const int kcol = (t & 15) << 3;
  const int vr = t >> 3;              // 0..31 (+c*32)
  const int vcol = (t & 7) << 3;

  bf16x8 ka[4];
  f16x8 va[4];
  // packed P of the previous tile: pa[slice], slice = mk*2+h, A[q=l31][k=8hi+j]
  f16x8 pa[4];

  // ---- prologue: stage tile 0, load tile 1, S^T(0), exp2, pack ----
#pragma unroll
  for (int c = 0; c < 4; c++)
    ka[c] = *(const bf16x8*)&Kw[(size_t)(kv_base + c * 16 + kr) * DDIM + kcol];
#pragma unroll
  for (int c = 0; c < 4; c++)
    va[c] = *(const f16x8*)&Vtw[(size_t)(c * 32 + vr) * LQ + kv_base + vcol];

#pragma unroll
  for (int c = 0; c < 4; c++)
    *(bf16x8*)&Kl[0][(c * 16 + kr) * 136 + kcol] = ka[c];
#pragma unroll
  for (int c = 0; c < 4; c++)
    *(f16x8*)&Vl[0][(c * 32 + vr) * 72 + vcol] = va[c];

#pragma unroll
  for (int c = 0; c < 4; c++)
    ka[c] = *(const bf16x8*)&Kw[(size_t)(kv_base + 64 + c * 16 + kr) * DDIM + kcol];
#pragma unroll
  for (int c = 0; c < 4; c++)
    va[c] = *(const f16x8*)&Vtw[(size_t)(c * 32 + vr) * LQ + kv_base + 64 + vcol];

  lds_barrier();

  f32x16 sv0 = z16, sv1 = z16;
  __builtin_amdgcn_s_setprio(1);
#pragma unroll
  for (int ks = 0; ks < 8; ks++) {
    bf16x8 kf0 = *(const bf16x8*)&Kl[0][l31 * 136 + ks * 16 + hi * 8];
    bf16x8 kf1 = *(const bf16x8*)&Kl[0][(32 + l31) * 136 + ks * 16 + hi * 8];
    sv0 = __builtin_amdgcn_mfma_f32_32x32x16_bf16(kf0, qf[ks], sv0, 0, 0, 0);
    sv1 = __builtin_amdgcn_mfma_f32_32x32x16_bf16(kf1, qf[ks], sv1, 0, 0, 0);
  }
  __builtin_amdgcn_s_setprio(0);
#pragma unroll
  for (int r = 0; r < 16; r++) {
    sv0[r] = __builtin_amdgcn_exp2f(sv0[r]);
    sv1[r] = __builtin_amdgcn_exp2f(sv1[r]);
  }
#pragma unroll
  for (int sl = 0; sl < 4; sl++) {    // slice = mk*2+h
    const int b = (sl & 1) * 8;
    float s0 = (sl >> 1) ? sv1[b + 0] : sv0[b + 0];
    float s1 = (sl >> 1) ? sv1[b + 1] : sv0[b + 1];
    float s2 = (sl >> 1) ? sv1[b + 2] : sv0[b + 2];
    float s3 = (sl >> 1) ? sv1[b + 3] : sv0[b + 3];
    float s4 = (sl >> 1) ? sv1[b + 4] : sv0[b + 4];
    float s5 = (sl >> 1) ? sv1[b + 5] : sv0[b + 5];
    float s6 = (sl >> 1) ? sv1[b + 6] : sv0[b + 6];
    float s7 = (sl >> 1) ? sv1[b + 7] : sv0[b + 7];
    uint32_t a0 = pkrtz(s0, s1);
    uint32_t a1 = pkrtz(s2, s3);
    uint32_t a2 = pkrtz(s4, s5);
    uint32_t a3 = pkrtz(s6, s7);
    asm("v_permlane32_swap_b32 %0, %1" : "+v"(a0), "+v"(a2));
    asm("v_permlane32_swap_b32 %0, %1" : "+v"(a1), "+v"(a3));
    u32x4 aw; aw.x = a0; aw.y = a1; aw.z = a2; aw.w = a3;
    pa[sl] = __builtin_bit_cast(f16x8, aw);
  }

  // ---- main pipeline: iter t computes S^T(t+1) ZIP PV(t) ----
  for (int tile = 0; tile < 15; tile++) {
    bf16* Kb = Kl[(tile + 1) & 1];
    f16*  Vb = Vl[(tile + 1) & 1];
    f16*  Vp = Vl[tile & 1];          // previous tile's V (PV operand)
#pragma unroll
    for (int c = 0; c < 4; c++)
      *(bf16x8*)&Kb[(c * 16 + kr) * 136 + kcol] = ka[c];
#pragma unroll
    for (int c = 0; c < 4; c++)
      *(f16x8*)&Vb[(c * 32 + vr) * 72 + vcol] = va[c];

    const int kvn = kv_base + (tile < 14 ? tile + 2 : 15) * 64;  // clamped prefetch
#pragma unroll
    for (int c = 0; c < 4; c++)
      ka[c] = *(const bf16x8*)&Kw[(size_t)(kvn + c * 16 + kr) * DDIM + kcol];
#pragma unroll
    for (int c = 0; c < 4; c++)
      va[c] = *(const f16x8*)&Vtw[(size_t)(c * 32 + vr) * LQ + kvn + vcol];

    lds_barrier();   // K/V(t+1) visible; prefetch loads stay in flight

    // ZIP: S^T(t+1) interleaved with PV(t) + li(t) — independent MFMA chains
    sv0 = z16; sv1 = z16;
    __builtin_amdgcn_s_setprio(1);
#pragma unroll
    for (int i = 0; i < 4; i++) {
      // S^T part: ks = 2i, 2i+1
      bf16x8 kf0a = *(const bf16x8*)&Kb[l31 * 136 + (2 * i) * 16 + hi * 8];
      bf16x8 kf1a = *(const bf16x8*)&Kb[(32 + l31) * 136 + (2 * i) * 16 + hi * 8];
      bf16x8 kf0b = *(const bf16x8*)&Kb[l31 * 136 + (2 * i + 1) * 16 + hi * 8];
      bf16x8 kf1b = *(const bf16x8*)&Kb[(32 + l31) * 136 + (2 * i + 1) * 16 + hi * 8];
      sv0 = __builtin_amdgcn_mfma_f32_32x32x16_bf16(kf0a, qf[2 * i], sv0, 0, 0, 0);
      sv1 = __builtin_amdgcn_mfma_f32_32x32x16_bf16(kf1a, qf[2 * i], sv1, 0, 0, 0);
      // PV part: slice i (mk = i>>1, h = i&1), operands from prev tile
      const int koff = (i >> 1) * 32 + (i & 1) * 16 + hi * 8;
#pragma unroll
      for (int dt = 0; dt < 4; dt++) {
        f16x8 vf = *(const f16x8*)&Vp[(dt * 32 + l31) * 72 + koff];
        o[dt] = __builtin_amdgcn_mfma_f32_32x32x16_f16(pa[i], vf, o[dt], 0, 0, 0);
      }
      liacc = __builtin_amdgcn_mfma_f32_32x32x16_f16(pa[i], ones, liacc, 0, 0, 0);
      sv0 = __builtin_amdgcn_mfma_f32_32x32x16_bf16(kf0b, qf[2 * i + 1], sv0, 0, 0, 0);
      sv1 = __builtin_amdgcn_mfma_f32_32x32x16_bf16(kf1b, qf[2 * i + 1], sv1, 0, 0, 0);
    }
    __builtin_amdgcn_s_setprio(0);

    // exp2(t+1) + pack(t+1) -> pa (VALU; overlaps other wave's ZIP)
#pragma unroll
    for (int r = 0; r < 16; r++) {
      sv0[r] = __builtin_amdgcn_exp2f(sv0[r]);
      sv1[r] = __builtin_amdgcn_exp2f(sv1[r]);
    }
#pragma unroll
    for (int sl = 0; sl < 4; sl++) {
      const int b = (sl & 1) * 8;
      float s0 = (sl >> 1) ? sv1[b + 0] : sv0[b + 0];
      float s1 = (sl >> 1) ? sv1[b + 1] : sv0[b + 1];
      float s2 = (sl >> 1) ? sv1[b + 2] : sv0[b + 2];
      float s3 = (sl >> 1) ? sv1[b + 3] : sv0[b + 3];
      float s4 = (sl >> 1) ? sv1[b + 4] : sv0[b + 4];
      float s5 = (sl >> 1) ? sv1[b + 5] : sv0[b + 5];
      float s6 = (sl >> 1) ? sv1[b + 6] : sv0[b + 6];
      float s7 = (sl >> 1) ? sv1[b + 7] : sv0[b + 7];
      uint32_t a0 = pkrtz(s0, s1);
      uint32_t a1 = pkrtz(s2, s3);
      uint32_t a2 = pkrtz(s4, s5);
      uint32_t a3 = pkrtz(s6, s7);
      asm("v_permlane32_swap_b32 %0, %1" : "+v"(a0), "+v"(a2));
      asm("v_permlane32_swap_b32 %0, %1" : "+v"(a1), "+v"(a3));
      u32x4 aw; aw.x = a0; aw.y = a1; aw.z = a2; aw.w = a3;
      pa[sl] = __builtin_bit_cast(f16x8, aw);
    }

    // RACE FIX: iter-t reads of Vl[tile&1] must complete before iter-(t+1)
    // staging overwrites it. All LDS reads are consumed above (compiler
    // lgkmcnt waits precede the consumer MFMAs), so a plain barrier suffices.
    __builtin_amdgcn_s_barrier();
  }

  // ---- epilogue: PV(15) ----
  {
    f16* Vp = Vl[15 & 1];
    __builtin_amdgcn_s_setprio(1);
#pragma unroll
    for (int i = 0; i < 4; i++) {
      const int koff = (i >> 1) * 32 + (i & 1) * 16 + hi * 8;
#pragma unroll
      for (int dt = 0; dt < 4; dt++) {
        f16x8 vf = *(const f16x8*)&Vp[(dt * 32 + l31) * 72 + koff];
        o[dt] = __builtin_amdgcn_mfma_f32_32x32x16_f16(pa[i], vf, o[dt], 0, 0, 0);
      }
      liacc = __builtin_amdgcn_mfma_f32_32x32x16_f16(pa[i], ones, liacc, 0, 0, 0);
    }
    __builtin_amdgcn_s_setprio(0);
  }

  // epilogue: unnormalized O (bf16) + row sums l
  const size_t po = (size_t)sp * LQ * DDIM;
#pragma unroll
  for (int dt = 0; dt < 4; dt++)
#pragma unroll
    for (int r = 0; r < 16; r++) {
      int q = q0w + (r & 3) + 8 * (r >> 2) + 4 * hi;
      Opb[po + (size_t)q * DDIM + dt * 32 + l31] = (bf16)o[dt][r];
    }
  if (l31 == 0) {
#pragma unroll
    for (int r = 0; r < 16; r++)
      lp[(size_t)sp * LQ + q0w + (r & 3) + 8 * (r >> 2) + 4 * hi] = liacc[r];
  }
}

// ---------------- K3: combine: out = (sum O_sp) / (sum l_sp) ----------------
__global__ void combine_kernel(const bf16* __restrict__ Opb, const float* __restrict__ lp,
                               float* __restrict__ out) {
  int idx = blockIdx.x * 256 + threadIdx.x;   // LQ * 32
  int q = idx >> 5;
  int d = (idx & 31) * 4;
  float lsum = 0.f;
  float acc[4] = {0.f, 0.f, 0.f, 0.f};
#pragma unroll
  for (int sp = 0; sp < NSPLIT; sp++) {
    lsum += lp[(size_t)sp * LQ + q];
    bf16x4 ov = *(const bf16x4*)&Opb[(size_t)sp * LQ * DDIM + (size_t)q * DDIM + d];
#pragma unroll
    for (int j = 0; j < 4; j++) acc[j] += (float)ov[j];
  }
  float inv = 1.0f / lsum;
  float4 r;
  r.x = acc[0] * inv; r.y = acc[1] * inv; r.z = acc[2] * inv; r.w = acc[3] * inv;
  *(float4*)&out[(size_t)q * DDIM + d] = r;
}

extern "C" void kernel_launch(void* const* d_in, const int* in_sizes, int n_in,
                              void* d_out, int out_size, void* d_ws, size_t ws_size,
                              hipStream_t stream) {
  const float* x  = (const float*)d_in[0];
  const float* Wq = (const float*)d_in[1];
  const float* bq = (const float*)d_in[2];
  const float* Wk = (const float*)d_in[3];
  const float* bk = (const float*)d_in[4];
  const float* Wv = (const float*)d_in[5];
  const float* bv = (const float*)d_in[6];
  char* ws = (char*)d_ws;
  bf16* Qw   = (bf16*)(ws);                              // 4 MB (prescaled by QS)
  bf16* Kw   = (bf16*)(ws + ((size_t)4 << 20));          // 4 MB
  f16*  Vtw  = (f16*)(ws + ((size_t)8 << 20));           // 4 MB (transposed [d][q], f16)
  bf16* Wt   = (bf16*)(ws + ((size_t)12 << 20));         // 768 KB
  float* bias_all = (float*)(ws + ((size_t)12 << 20) + 786432); // 1.5 KB
  bf16* Opb  = (bf16*)(ws + ((size_t)13 << 20));         // 16 MB (4 splits, bf16)
  float* lpp = (float*)(ws + ((size_t)29 << 20));        // 256 KB
  float* out = (float*)d_out;

  prep_kernel<<<1536, 256, 0, stream>>>(Wq, Wk, Wv, bq, bk, bv, Wt, bias_all);
  qkv_gemm<<<256, 512, 0, stream>>>(x, Wt, bias_all, Qw, Kw, Vtw);
  flash_kernel<<<dim3(128, NSPLIT), 256, 0, stream>>>(Qw, Kw, Vtw, Opb, lpp);
  combine_kernel<<<2048, 256, 0, stream>>>(Opb, lpp, out);
}